// Round 11
// baseline (35.403 us; speedup 1.0000x reference)
//
#include <hip/hip_runtime.h>
#include <math.h>

// HAKE scoring for MI355X — round 11: dot2 inner loop.
// R10 lesson: main ~28us ~= LDS-pipe(12.5us/CU) + VALU(10.7us/SIMD) poorly
// overlapped. Inner body was 5 VALU/triple (2 unpack + mul + fma + abs-add).
// Now: head X=(-ca,sa) and tail W=(sb,cb) stored as packed half2;
// sin(a-b) = dot2(X,W) -> v_dot2_f32_f16 + abs-add = 2 VALU/triple, zero
// unpack. VALU 10.7 -> 4.7us/SIMD; LDS unchanged -> single clear bound.
// f16 is more precise than R10's bf16 (which passed). Rest identical.

#define D_   256
#define N_   20000
#define NT   16
#define NBLK (N_ / NT)      // 1250

// rev units for sin(x/2): 1/(4*EMB_RANGE)
#define K2S 4.571428571428571f

// ws layout (bytes)
#define WS_A1 0
#define WS_A2 16384
#define WS_SC 32768
#define WS_S0 65536

typedef short short8 __attribute__((ext_vector_type(8)));
typedef float f32x4  __attribute__((ext_vector_type(4)));
typedef _Float16 half2_t __attribute__((ext_vector_type(2)));

union PKH { unsigned u; half2_t h; };

__device__ __forceinline__ float sinrev_(float x) { return __builtin_amdgcn_sinf(x); }
__device__ __forceinline__ float cosrev_(float x) { return __builtin_amdgcn_cosf(x); }

__device__ __forceinline__ unsigned short bf16r(float x) {
    union { float f; unsigned u; } v; v.f = x;
    return (unsigned short)((v.u + 0x7FFFu + ((v.u >> 16) & 1u)) >> 16);
}

__device__ __forceinline__ short8 pack8(float4 a, float4 b, bool sq) {
    float v[8] = {a.x, a.y, a.z, a.w, b.x, b.y, b.z, b.w};
    short8 r;
#pragma unroll
    for (int i = 0; i < 8; ++i) { float x = sq ? v[i] * v[i] : v[i]; r[i] = (short)bf16r(x); }
    return r;
}

// ---------------------------------------------------------------------------
// K0: per-(b,d) precompute. 32 blocks x 256 thr. A1/A2 (bf16 GEMM tables),
// SC = packed half2 X=(-cos,sin) of scaled head+rel phase, S0 = sum mh'^2.
// ---------------------------------------------------------------------------
__global__ __launch_bounds__(256)
void hake_prep(const int* __restrict__ e1, const int* __restrict__ rel,
               const float* __restrict__ emb_e, const float* __restrict__ emb_rel,
               char* __restrict__ ws)
{
    __shared__ float sp[4];
    const int b = blockIdx.x, d = threadIdx.x;
    const int he = e1[b], hr = rel[b];
    const float ph = emb_e[(size_t)he * 512 + d];
    const float mh = emb_e[(size_t)he * 512 + 256 + d];
    const float pr = emb_rel[(size_t)hr * 768 + d];
    const float mr = emb_rel[(size_t)hr * 768 + 256 + d];
    const float bi = emb_rel[(size_t)hr * 768 + 512 + d];

    const float a = (ph + pr) * K2S;
    PKH x;
    x.h.x = (_Float16)(-cosrev_(a));
    x.h.y = (_Float16)(sinrev_(a));
    ((unsigned*)(ws + WS_SC))[b * 256 + d] = x.u;

    const float mra = fabsf(mr);
    float bic = fminf(bi, 1.0f);
    bic = (bic < -mra) ? -mra : bic;
    const float cc  = 1.0f - bic;
    const float mhp = mh * (mra + bic);
    ((short*)(ws + WS_A1))[b * 256 + d] = (short)bf16r(cc * cc);
    ((short*)(ws + WS_A2))[b * 256 + d] = (short)bf16r(-2.0f * mhp * cc);

    float s0 = mhp * mhp;
#pragma unroll
    for (int o = 1; o < 64; o <<= 1) s0 += __shfl_xor(s0, o, 64);
    if ((threadIdx.x & 63) == 0) sp[threadIdx.x >> 6] = s0;
    __syncthreads();
    if (threadIdx.x == 0)
        ((float*)(ws + WS_S0))[b] = sp[0] + sp[1] + sp[2] + sp[3];
}

// ---------------------------------------------------------------------------
// Main: grid 1250 x 512. LDS: Pb (packed half2 W=(sb,cb), 16KB) + U (17.4KB).
// Inner: 1 b128 read = 4 d; per triple: v_dot2_f32_f16 + v_add_f32(|.|).
// ---------------------------------------------------------------------------
__global__ __launch_bounds__(512, 8)
void hake_main(const float* __restrict__ emb_e,
               const char* __restrict__ ws,
               const float* __restrict__ pw_p, const float* __restrict__ mw_p,
               float* __restrict__ out)
{
    __shared__ unsigned Pb[NT * 256];    // 16 KB packed (sb,cb) half2
    __shared__ float U[4352];            // redr[8][32][17] | redf[8][16][32]

    const int t   = threadIdx.x;
    const int l   = t & 63;
    const int w   = t >> 6;       // wave 0..7
    const int b   = t & 31;
    const int g   = t >> 5;       // d-group 0..15
    const int dlo = g * 16;
    const int fr  = l & 15;
    const int hi  = l >> 4;
    const int n0  = blockIdx.x * NT;

    const short*    A1w = (const short*)(ws + WS_A1);
    const short*    A2w = (const short*)(ws + WS_A2);
    const unsigned* SCw = (const unsigned*)(ws + WS_SC);
    const float*    S0w = (const float*)(ws + WS_S0);

    // ---- B-frag loads (mod half of 16 tail rows) ---------------------------
    const int term  = w >> 2;
    const int dbase = (w & 3) * 64;
    const float* mtp = emb_e + (size_t)(n0 + fr) * (2 * D_) + D_;
    float4 bva0 = *(const float4*)(mtp + dbase + hi * 8);
    float4 bvb0 = *(const float4*)(mtp + dbase + hi * 8 + 4);
    float4 bva1 = *(const float4*)(mtp + dbase + 32 + hi * 8);
    float4 bvb1 = *(const float4*)(mtp + dbase + 32 + hi * 8 + 4);

    // ---- phase-row loads: rows 2w,2w+1; d = 2l, 128+2l ---------------------
    const float* prow0 = emb_e + (size_t)(n0 + w * 2) * (2 * D_);
    const float* prow1 = emb_e + (size_t)(n0 + w * 2 + 1) * (2 * D_);
    float2 lp00 = *(const float2*)(prow0 + 2 * l);
    float2 lp01 = *(const float2*)(prow0 + 128 + 2 * l);
    float2 lp10 = *(const float2*)(prow1 + 2 * l);
    float2 lp11 = *(const float2*)(prow1 + 128 + 2 * l);

    // ---- A-frag loads from ws (L2-hot) -------------------------------------
    const short* At = term ? A2w : A1w;
    short8 a00 = *(const short8*)(At + fr * 256 + dbase + hi * 8);
    short8 a01 = *(const short8*)(At + fr * 256 + dbase + 32 + hi * 8);
    short8 a10 = *(const short8*)(At + (16 + fr) * 256 + dbase + hi * 8);
    short8 a11 = *(const short8*)(At + (16 + fr) * 256 + dbase + 32 + hi * 8);

    // ---- stage Pb: W = (sin, cos) packed half2 -----------------------------
    {
        PKH w0, w1;
        float v0, v1;
        v0 = lp00.x * K2S; v1 = lp00.y * K2S;
        w0.h.x = (_Float16)sinrev_(v0); w0.h.y = (_Float16)cosrev_(v0);
        w1.h.x = (_Float16)sinrev_(v1); w1.h.y = (_Float16)cosrev_(v1);
        *(uint2*)(&Pb[(w * 2) * 256 + 2 * l]) = make_uint2(w0.u, w1.u);
        v0 = lp01.x * K2S; v1 = lp01.y * K2S;
        w0.h.x = (_Float16)sinrev_(v0); w0.h.y = (_Float16)cosrev_(v0);
        w1.h.x = (_Float16)sinrev_(v1); w1.h.y = (_Float16)cosrev_(v1);
        *(uint2*)(&Pb[(w * 2) * 256 + 128 + 2 * l]) = make_uint2(w0.u, w1.u);
        v0 = lp10.x * K2S; v1 = lp10.y * K2S;
        w0.h.x = (_Float16)sinrev_(v0); w0.h.y = (_Float16)cosrev_(v0);
        w1.h.x = (_Float16)sinrev_(v1); w1.h.y = (_Float16)cosrev_(v1);
        *(uint2*)(&Pb[(w * 2 + 1) * 256 + 2 * l]) = make_uint2(w0.u, w1.u);
        v0 = lp11.x * K2S; v1 = lp11.y * K2S;
        w0.h.x = (_Float16)sinrev_(v0); w0.h.y = (_Float16)cosrev_(v0);
        w1.h.x = (_Float16)sinrev_(v1); w1.h.y = (_Float16)cosrev_(v1);
        *(uint2*)(&Pb[(w * 2 + 1) * 256 + 128 + 2 * l]) = make_uint2(w0.u, w1.u);
    }

    // ---- r-term MFMAs (A from ws, B packed from mt loads) ------------------
    {
        short8 bf0 = pack8(bva0, bvb0, term == 0);
        short8 bf1 = pack8(bva1, bvb1, term == 0);
        f32x4 acc0 = {0.f, 0.f, 0.f, 0.f};
        f32x4 acc1 = {0.f, 0.f, 0.f, 0.f};
        acc0 = __builtin_amdgcn_mfma_f32_16x16x32_bf16(a00, bf0, acc0, 0, 0, 0);
        acc0 = __builtin_amdgcn_mfma_f32_16x16x32_bf16(a01, bf1, acc0, 0, 0, 0);
        acc1 = __builtin_amdgcn_mfma_f32_16x16x32_bf16(a10, bf0, acc1, 0, 0, 0);
        acc1 = __builtin_amdgcn_mfma_f32_16x16x32_bf16(a11, bf1, acc1, 0, 0, 0);
        // C/D map (verified): col = lane&15 (n), row = hi*4 + reg (b)
#pragma unroll
        for (int r = 0; r < 4; ++r) {
            U[(w * 32 + hi * 4 + r) * 17 + fr]      = acc0[r];
            U[(w * 32 + 16 + hi * 4 + r) * 17 + fr] = acc1[r];
        }
    }
    __syncthreads();                                    // b1

    // ---- r reduce: thread t -> (b = t&31, n = t>>5) ------------------------
    const int fn = t >> 5, fb = t & 31;
    float rr = 0.0f;
#pragma unroll
    for (int ww = 0; ww < 8; ++ww) rr += U[(ww * 32 + fb) * 17 + fn];

    // ---- X loads (packed half2 (-ca,sa)), L2-hot ---------------------------
    half2_t Xr[16];
    {
        uint4 s0 = *(const uint4*)(SCw + b * 256 + dlo);
        uint4 s1 = *(const uint4*)(SCw + b * 256 + dlo + 4);
        uint4 s2 = *(const uint4*)(SCw + b * 256 + dlo + 8);
        uint4 s3 = *(const uint4*)(SCw + b * 256 + dlo + 12);
        Xr[0]  = __builtin_bit_cast(half2_t, s0.x);
        Xr[1]  = __builtin_bit_cast(half2_t, s0.y);
        Xr[2]  = __builtin_bit_cast(half2_t, s0.z);
        Xr[3]  = __builtin_bit_cast(half2_t, s0.w);
        Xr[4]  = __builtin_bit_cast(half2_t, s1.x);
        Xr[5]  = __builtin_bit_cast(half2_t, s1.y);
        Xr[6]  = __builtin_bit_cast(half2_t, s1.z);
        Xr[7]  = __builtin_bit_cast(half2_t, s1.w);
        Xr[8]  = __builtin_bit_cast(half2_t, s2.x);
        Xr[9]  = __builtin_bit_cast(half2_t, s2.y);
        Xr[10] = __builtin_bit_cast(half2_t, s2.z);
        Xr[11] = __builtin_bit_cast(half2_t, s2.w);
        Xr[12] = __builtin_bit_cast(half2_t, s3.x);
        Xr[13] = __builtin_bit_cast(half2_t, s3.y);
        Xr[14] = __builtin_bit_cast(half2_t, s3.z);
        Xr[15] = __builtin_bit_cast(half2_t, s3.w);
    }

    // ---- phase accumulate: 2 VALU/triple (dot2 + abs-add) ------------------
    float sph[NT];
#pragma unroll
    for (int j = 0; j < NT; ++j) sph[j] = 0.0f;

#pragma unroll
    for (int q = 0; q < 4; ++q) {
        const half2_t x0 = Xr[q * 4 + 0];
        const half2_t x1 = Xr[q * 4 + 1];
        const half2_t x2 = Xr[q * 4 + 2];
        const half2_t x3 = Xr[q * 4 + 3];
#pragma unroll
        for (int j = 0; j < NT; ++j) {
            uint4 tv = *(const uint4*)(&Pb[j * 256 + dlo + q * 4]);   // bcast
            sph[j] += fabsf(__builtin_amdgcn_fdot2(x0, __builtin_bit_cast(half2_t, tv.x), 0.0f, false));
            sph[j] += fabsf(__builtin_amdgcn_fdot2(x1, __builtin_bit_cast(half2_t, tv.y), 0.0f, false));
            sph[j] += fabsf(__builtin_amdgcn_fdot2(x2, __builtin_bit_cast(half2_t, tv.z), 0.0f, false));
            sph[j] += fabsf(__builtin_amdgcn_fdot2(x3, __builtin_bit_cast(half2_t, tv.w), 0.0f, false));
        }
    }

    // ---- phase reduce ------------------------------------------------------
#pragma unroll
    for (int j = 0; j < NT; ++j) sph[j] += __shfl_xor(sph[j], 32, 64);
    __syncthreads();                                    // b2: redr consumed
    if (l < 32) {
#pragma unroll
        for (int j = 0; j < NT; ++j) U[(w * 16 + j) * 32 + l] = sph[j];
    }
    __syncthreads();                                    // b3: redf ready

    // ---- finalize: thread t -> (b = fb, n = n0 + fn) -----------------------
    {
        float pa = 0.0f;
#pragma unroll
        for (int ww = 0; ww < 8; ++ww) pa += U[(ww * 16 + fn) * 32 + fb];
        float rfull = fmaxf(rr + S0w[fb], 0.0f);
        float z = fmaf(pa, pw_p[0], sqrtf(rfull) * mw_p[0]) - 12.0f;  // GAMMA
        out[(size_t)fb * N_ + (n0 + fn)] = 1.0f / (1.0f + __expf(z));
    }
}

extern "C" void kernel_launch(void* const* d_in, const int* in_sizes, int n_in,
                              void* d_out, int out_size, void* d_ws, size_t ws_size,
                              hipStream_t stream)
{
    // inputs: 0:g 1:e1 2:rel 3:e2_multi(unused) 4:emb_e 5:emb_rel 6:phase_w 7:mod_w
    const int*   e1      = (const int*)d_in[1];
    const int*   rel     = (const int*)d_in[2];
    const float* emb_e   = (const float*)d_in[4];
    const float* emb_rel = (const float*)d_in[5];
    const float* pw      = (const float*)d_in[6];
    const float* mw      = (const float*)d_in[7];
    float* out = (float*)d_out;

    hipLaunchKernelGGL(hake_prep, dim3(32), dim3(256), 0, stream,
                       e1, rel, emb_e, emb_rel, (char*)d_ws);
    hipLaunchKernelGGL(hake_main, dim3(NBLK), dim3(512), 0, stream,
                       emb_e, (const char*)d_ws, pw, mw, out);
}